// Round 7
// baseline (186.012 us; speedup 1.0000x reference)
//
#include <hip/hip_runtime.h>

#define NFEAT 128
#define HID 16
#define NCLS 40
#define BSHIFT 7                 // 128 nodes per bucket
#define BNODES 128
#define CAP 2560                 // slab capacity per bucket (Poisson mean ~2046, 11 sigma)
#define NBUCK_MAX 800            // >= ceil(100000/128)=782
#define BIN_CHUNK 4096           // edges per bin block (16 per thread)

#define SCALE1 262144.0f         // 2^18 — layer-1 message quantization
#define SCALE2 65536.0f          // 2^16 — layer-2 message quantization

__device__ __forceinline__ unsigned bf16_rne(float f) {
    unsigned u = __float_as_uint(f);
    return (u + 0x7FFFu + ((u >> 16) & 1u)) >> 16;
}
__device__ __forceinline__ float bf_lo(unsigned u) { return __uint_as_float(u << 16); }
__device__ __forceinline__ float bf_hi(unsigned u) { return __uint_as_float(u & 0xFFFF0000u); }

// ---------- fused: bin (blocks 0..nbin-1) + gemm1 (blocks nbin..) ----------
// bin:  slab[b*CAP + i] = { src | (dst&127)<<20 , bits(weight) }, cursor[b] = count
// gemm1: h1b = bf16(x @ W1)

__global__ __launch_bounds__(256) void fused_bin_gemm1_kernel(
        const int* __restrict__ src, const int* __restrict__ dst,
        const float* __restrict__ ew, int* __restrict__ cursor,
        int2* __restrict__ slab, int E, int nbuck, int nbin,
        const float* __restrict__ x, const float* __restrict__ W1,
        unsigned short* __restrict__ h1b, int n)
{
    __shared__ float smem[80 * 132];          // 42.2 KB union
    int tid = threadIdx.x;

    if (blockIdx.x < (unsigned)nbin) {
        // ---------------- bin ----------------
        int* hist    = (int*)smem;            // [NBUCK_MAX]
        int* runbase = hist + NBUCK_MAX;      // [NBUCK_MAX]
        for (int i = tid; i < NBUCK_MAX; i += 256) hist[i] = 0;
        __syncthreads();

        int base = blockIdx.x * BIN_CHUNK;
        int myd[16], mys[16], myw[16];
        #pragma unroll
        for (int k = 0; k < 16; ++k) {
            int e = base + k * 256 + tid;
            if (e < E) {
                myd[k] = dst[e];
                mys[k] = src[e];
                myw[k] = __float_as_int(ew[e]);
                atomicAdd(&hist[myd[k] >> BSHIFT], 1);    // native ds_add
            } else myd[k] = -1;
        }
        __syncthreads();
        for (int i = tid; i < nbuck; i += 256) {
            int c = hist[i];
            runbase[i] = c ? (i * CAP + atomicAdd(&cursor[i], c)) : 0;
            hist[i] = 0;                                  // reuse as intra-block cursor
        }
        __syncthreads();
        #pragma unroll
        for (int k = 0; k < 16; ++k) {
            int d = myd[k];
            if (d >= 0) {
                int b = d >> BSHIFT;
                int pos = runbase[b] + atomicAdd(&hist[b], 1);
                if (pos < (b + 1) * CAP)                  // overflow guard
                    slab[pos] = make_int2(mys[k] | ((d & (BNODES - 1)) << 20), myw[k]);
            }
        }
    } else {
        // ---------------- gemm1 ----------------
        float* xs = smem;                     // 64 x 132
        float* ws = smem + 64 * 132;          // 16 x 132
        int r0 = (blockIdx.x - nbin) * 64;
        int rows = n - r0; if (rows > 64) rows = 64;

        const float4* xg = (const float4*)(x + (size_t)r0 * NFEAT);
        #pragma unroll
        for (int i = 0; i < 8; ++i) {
            int flat4 = i * 256 + tid;
            int row = flat4 >> 5, k4 = flat4 & 31;
            float4 v = make_float4(0.f, 0.f, 0.f, 0.f);
            if (row < rows) v = xg[flat4];
            *(float4*)&xs[row * 132 + k4 * 4] = v;
        }
        for (int i = tid; i < HID * NFEAT; i += 256) {
            int c = i >> 7, k = i & 127;
            ws[c * 132 + k] = W1[k * HID + c];
        }
        __syncthreads();

        int row = tid >> 2;
        int c0  = (tid & 3) * 4;
        float acc[4] = {0.f, 0.f, 0.f, 0.f};
        #pragma unroll 4
        for (int k4 = 0; k4 < 32; ++k4) {
            float4 xv = *(const float4*)&xs[row * 132 + k4 * 4];
            #pragma unroll
            for (int i = 0; i < 4; ++i) {
                float4 wv = *(const float4*)&ws[(c0 + i) * 132 + k4 * 4];
                acc[i] += xv.x * wv.x + xv.y * wv.y + xv.z * wv.z + xv.w * wv.w;
            }
        }
        if (row < rows) {
            unsigned lo = bf16_rne(acc[0]) | (bf16_rne(acc[1]) << 16);
            unsigned hi = bf16_rne(acc[2]) | (bf16_rne(acc[3]) << 16);
            *(uint2*)(h1b + (size_t)(r0 + row) * HID + c0) = make_uint2(lo, hi);
        }
    }
}

// ---------- gather layer 1: fixed-point LDS accumulation, bf16 output ----------
__global__ __launch_bounds__(512) void gather1_kernel(const uint4* __restrict__ hq,
                                                      const int* __restrict__ cursor,
                                                      const int2* __restrict__ slab,
                                                      uint4* __restrict__ outb, int n)
{
    __shared__ int accum[HID * BNODES];   // 8 KB, [f][dl]
    int tid = threadIdx.x;
    #pragma unroll
    for (int i = tid; i < HID * BNODES; i += 512) accum[i] = 0;
    __syncthreads();

    int b = blockIdx.x;
    int beg = b * CAP;
    int cnt = cursor[b]; if (cnt > CAP) cnt = CAP;

    int tasks = cnt * 2;                  // 2 lanes per edge, 8 feats each
    for (int i = tid; i < tasks; i += 512) {
        int2 e = slab[beg + (i >> 1)];
        int p = i & 1;
        int s  = e.x & 0xFFFFF;
        int dl = (e.x >> 20) & (BNODES - 1);
        float wsc = __int_as_float(e.y) * SCALE1;
        uint4 q = hq[(size_t)s * 2 + p];
        int* a = &accum[(p * 8) * BNODES + dl];
        atomicAdd(a + 0 * BNODES, __float2int_rn(wsc * bf_lo(q.x)));
        atomicAdd(a + 1 * BNODES, __float2int_rn(wsc * bf_hi(q.x)));
        atomicAdd(a + 2 * BNODES, __float2int_rn(wsc * bf_lo(q.y)));
        atomicAdd(a + 3 * BNODES, __float2int_rn(wsc * bf_hi(q.y)));
        atomicAdd(a + 4 * BNODES, __float2int_rn(wsc * bf_lo(q.z)));
        atomicAdd(a + 5 * BNODES, __float2int_rn(wsc * bf_hi(q.z)));
        atomicAdd(a + 6 * BNODES, __float2int_rn(wsc * bf_lo(q.w)));
        atomicAdd(a + 7 * BNODES, __float2int_rn(wsc * bf_hi(q.w)));
    }
    __syncthreads();

    const float inv = 1.0f / SCALE1;
    if (tid < BNODES * 2) {
        int dl = tid >> 1, p = tid & 1;
        int node = (b << BSHIFT) + dl;
        if (node < n) {
            uint4 qs = hq[(size_t)node * 2 + p];
            const int* a = &accum[(p * 8) * BNODES + dl];
            uint4 o;
            o.x = bf16_rne((float)a[0 * BNODES] * inv + bf_lo(qs.x)) |
                  (bf16_rne((float)a[1 * BNODES] * inv + bf_hi(qs.x)) << 16);
            o.y = bf16_rne((float)a[2 * BNODES] * inv + bf_lo(qs.y)) |
                  (bf16_rne((float)a[3 * BNODES] * inv + bf_hi(qs.y)) << 16);
            o.z = bf16_rne((float)a[4 * BNODES] * inv + bf_lo(qs.z)) |
                  (bf16_rne((float)a[5 * BNODES] * inv + bf_hi(qs.z)) << 16);
            o.w = bf16_rne((float)a[6 * BNODES] * inv + bf_lo(qs.w)) |
                  (bf16_rne((float)a[7 * BNODES] * inv + bf_hi(qs.w)) << 16);
            outb[(size_t)node * 2 + p] = o;
        }
    }
}

// ---------- gather layer 2 + W2 projection + log_softmax, fused ----------
#define ZPAD 41                  // pad-41 stride: conflict-free LDS staging
__global__ __launch_bounds__(512) void gather2_lsm_kernel(const uint4* __restrict__ hq,
                                                          const int* __restrict__ cursor,
                                                          const int2* __restrict__ slab,
                                                          const float* __restrict__ W2,
                                                          float* __restrict__ out, int n)
{
    __shared__ int   accum[HID * BNODES];   // 8 KB
    __shared__ float w2s[HID * NCLS];       // 2.56 KB
    __shared__ float zbuf[BNODES * ZPAD];   // 21 KB
    int tid = threadIdx.x;
    #pragma unroll
    for (int i = tid; i < HID * BNODES; i += 512) accum[i] = 0;
    for (int i = tid; i < HID * NCLS; i += 512) w2s[i] = W2[i];
    __syncthreads();

    int b = blockIdx.x;
    int beg = b * CAP;
    int cnt = cursor[b]; if (cnt > CAP) cnt = CAP;
    int node0 = b << BSHIFT;

    int tasks = cnt * 2;
    for (int i = tid; i < tasks; i += 512) {
        int2 e = slab[beg + (i >> 1)];
        int p = i & 1;
        int s  = e.x & 0xFFFFF;
        int dl = (e.x >> 20) & (BNODES - 1);
        float wsc = __int_as_float(e.y) * SCALE2;
        uint4 q = hq[(size_t)s * 2 + p];
        int* a = &accum[(p * 8) * BNODES + dl];
        atomicAdd(a + 0 * BNODES, __float2int_rn(wsc * bf_lo(q.x)));
        atomicAdd(a + 1 * BNODES, __float2int_rn(wsc * bf_hi(q.x)));
        atomicAdd(a + 2 * BNODES, __float2int_rn(wsc * bf_lo(q.y)));
        atomicAdd(a + 3 * BNODES, __float2int_rn(wsc * bf_hi(q.y)));
        atomicAdd(a + 4 * BNODES, __float2int_rn(wsc * bf_lo(q.z)));
        atomicAdd(a + 5 * BNODES, __float2int_rn(wsc * bf_hi(q.z)));
        atomicAdd(a + 6 * BNODES, __float2int_rn(wsc * bf_lo(q.w)));
        atomicAdd(a + 7 * BNODES, __float2int_rn(wsc * bf_hi(q.w)));
    }
    __syncthreads();

    // per-node epilogue: r[16] -> z[40] -> log_softmax -> zbuf
    const float inv = 1.0f / SCALE2;
    if (tid < BNODES) {
        int dl = tid;
        int node = node0 + dl;
        if (node < n) {
            uint4 q0 = hq[(size_t)node * 2 + 0];
            uint4 q1 = hq[(size_t)node * 2 + 1];
            float r[HID];
            r[0]  = (float)accum[ 0 * BNODES + dl] * inv + bf_lo(q0.x);
            r[1]  = (float)accum[ 1 * BNODES + dl] * inv + bf_hi(q0.x);
            r[2]  = (float)accum[ 2 * BNODES + dl] * inv + bf_lo(q0.y);
            r[3]  = (float)accum[ 3 * BNODES + dl] * inv + bf_hi(q0.y);
            r[4]  = (float)accum[ 4 * BNODES + dl] * inv + bf_lo(q0.z);
            r[5]  = (float)accum[ 5 * BNODES + dl] * inv + bf_hi(q0.z);
            r[6]  = (float)accum[ 6 * BNODES + dl] * inv + bf_lo(q0.w);
            r[7]  = (float)accum[ 7 * BNODES + dl] * inv + bf_hi(q0.w);
            r[8]  = (float)accum[ 8 * BNODES + dl] * inv + bf_lo(q1.x);
            r[9]  = (float)accum[ 9 * BNODES + dl] * inv + bf_hi(q1.x);
            r[10] = (float)accum[10 * BNODES + dl] * inv + bf_lo(q1.y);
            r[11] = (float)accum[11 * BNODES + dl] * inv + bf_hi(q1.y);
            r[12] = (float)accum[12 * BNODES + dl] * inv + bf_lo(q1.z);
            r[13] = (float)accum[13 * BNODES + dl] * inv + bf_hi(q1.z);
            r[14] = (float)accum[14 * BNODES + dl] * inv + bf_lo(q1.w);
            r[15] = (float)accum[15 * BNODES + dl] * inv + bf_hi(q1.w);

            float z[NCLS];
            #pragma unroll
            for (int j = 0; j < NCLS; ++j) z[j] = 0.f;
            #pragma unroll
            for (int f = 0; f < HID; ++f) {
                float rf = r[f];
                #pragma unroll
                for (int j = 0; j < NCLS; ++j)
                    z[j] += rf * w2s[f * NCLS + j];   // same addr all lanes: broadcast
            }
            float m = z[0];
            #pragma unroll
            for (int j = 1; j < NCLS; ++j) m = fmaxf(m, z[j]);
            float ssum = 0.f;
            #pragma unroll
            for (int j = 0; j < NCLS; ++j) ssum += __expf(z[j] - m);
            float l = m + __logf(ssum);
            #pragma unroll
            for (int j = 0; j < NCLS; ++j) zbuf[dl * ZPAD + j] = z[j] - l;
        }
    }
    __syncthreads();

    // coalesced out write: contiguous 20 KB per block
    for (int i = tid; i < BNODES * NCLS; i += 512) {
        int nl = i / NCLS, j = i - nl * NCLS;
        if (node0 + nl < n)
            out[(size_t)node0 * NCLS + i] = zbuf[nl * ZPAD + j];
    }
}

extern "C" void kernel_launch(void* const* d_in, const int* in_sizes, int n_in,
                              void* d_out, int out_size, void* d_ws, size_t ws_size,
                              hipStream_t stream)
{
    const float* x  = (const float*)d_in[0];
    const float* ew = (const float*)d_in[1];
    const float* W1 = (const float*)d_in[2];
    const float* W2 = (const float*)d_in[3];
    const int*   ei = (const int*)d_in[4];

    int n = in_sizes[0] / NFEAT;     // 100000
    int E = in_sizes[1];             // 1600000
    const int* src = ei;
    const int* dst = ei + E;
    float* out = (float*)d_out;

    int nbuck = (n + BNODES - 1) >> BSHIFT;           // 782
    int nbin  = (E + BIN_CHUNK - 1) / BIN_CHUNK;      // 391
    int ngemm = (n + 63) / 64;                        // 1563

    // ---- workspace layout ----
    char* w = (char*)d_ws;
    int*  cursor = (int*)w;  w += NBUCK_MAX * 4;
    w = (char*)(((size_t)w + 15) & ~(size_t)15);
    int2* slab   = (int2*)w; w += (size_t)NBUCK_MAX * CAP * 8;           // 16 MB
    unsigned short* h1b = (unsigned short*)w; w += (size_t)n * HID * 2;  // 3.2 MB bf16
    unsigned short* h2b = (unsigned short*)w; w += (size_t)n * HID * 2;  // 3.2 MB bf16

    hipMemsetAsync(cursor, 0, (size_t)nbuck * 4, stream);
    fused_bin_gemm1_kernel<<<nbin + ngemm, 256, 0, stream>>>(
        src, dst, ew, cursor, slab, E, nbuck, nbin, x, W1, h1b, n);
    gather1_kernel<<<nbuck, 512, 0, stream>>>((const uint4*)h1b, cursor, slab,
                                              (uint4*)h2b, n);
    gather2_lsm_kernel<<<nbuck, 512, 0, stream>>>((const uint4*)h2b, cursor, slab,
                                                  W2, out, n);
}

// Round 8
// 174.963 us; speedup vs baseline: 1.0631x; 1.0631x over previous
//
#include <hip/hip_runtime.h>

#define NFEAT 128
#define HID 16
#define NCLS 40
#define BSHIFT 7                 // 128 nodes per bucket
#define BNODES 128
#define CAP 2560                 // slab capacity per bucket (Poisson mean ~2046, 11 sigma)
#define NBUCK_MAX 800            // >= ceil(100000/128)=782
#define BIN_CHUNK 4096           // edges per bin block (16 per thread)
#define APAD 17                  // accum stride: lane's 8 atomics -> 8 distinct banks

#define SCALE1 262144.0f         // 2^18 — layer-1 message quantization
#define SCALE2 65536.0f          // 2^16 — layer-2 message quantization

typedef __attribute__((ext_vector_type(8))) short short8;   // 8 x bf16 (4 VGPRs)
typedef __attribute__((ext_vector_type(4))) float f32x4;

__device__ __forceinline__ unsigned bf16_rne(float f) {
    unsigned u = __float_as_uint(f);
    return (u + 0x7FFFu + ((u >> 16) & 1u)) >> 16;
}
__device__ __forceinline__ float bf_lo(unsigned u) { return __uint_as_float(u << 16); }
__device__ __forceinline__ float bf_hi(unsigned u) { return __uint_as_float(u & 0xFFFF0000u); }

// ---------- bin: bucket slabs (standalone, 6.4 KB LDS -> high occupancy) ----------
// slab[b*CAP + i] = { src | (dst&127)<<20 , bits(weight) }, cursor[b] = count
__global__ __launch_bounds__(256) void bin_kernel(const int* __restrict__ src,
                                                  const int* __restrict__ dst,
                                                  const float* __restrict__ ew,
                                                  int* __restrict__ cursor,
                                                  int2* __restrict__ slab,
                                                  int E, int nbuck)
{
    __shared__ int hist[NBUCK_MAX];
    __shared__ int runbase[NBUCK_MAX];
    int tid = threadIdx.x;
    for (int i = tid; i < NBUCK_MAX; i += 256) hist[i] = 0;
    __syncthreads();

    int base = blockIdx.x * BIN_CHUNK;
    int myd[16], mys[16], myw[16];
    #pragma unroll
    for (int k = 0; k < 16; ++k) {
        int e = base + k * 256 + tid;
        if (e < E) {
            myd[k] = dst[e];
            mys[k] = src[e];
            myw[k] = __float_as_int(ew[e]);
            atomicAdd(&hist[myd[k] >> BSHIFT], 1);       // native ds_add
        } else myd[k] = -1;
    }
    __syncthreads();
    for (int i = tid; i < nbuck; i += 256) {
        int c = hist[i];
        runbase[i] = c ? (i * CAP + atomicAdd(&cursor[i], c)) : 0;
        hist[i] = 0;                                     // reuse as intra-block cursor
    }
    __syncthreads();
    #pragma unroll
    for (int k = 0; k < 16; ++k) {
        int d = myd[k];
        if (d >= 0) {
            int b = d >> BSHIFT;
            int pos = runbase[b] + atomicAdd(&hist[b], 1);
            if (pos < (b + 1) * CAP)                     // overflow guard
                slab[pos] = make_int2(mys[k] | ((d & (BNODES - 1)) << 20), myw[k]);
        }
    }
}

// ---------- gemm1: h1b = bf16(x @ W1) via MFMA, no LDS ----------
// One wave = one 16-row M-tile. A: x rows (f32->bf16 in regs). B: W1 frags in regs.
// A-frag:  A[m=lane&15][k=(lane>>4)*8+j]
// B-frag:  B[k=(lane>>4)*8+j][n=lane&15]
// D-frag:  D[row=(lane>>4)*4+reg][col=lane&15]
__global__ __launch_bounds__(256) void gemm1_mfma_kernel(const float* __restrict__ x,
                                                         const float* __restrict__ W1,
                                                         unsigned short* __restrict__ h1b,
                                                         int n)
{
    int tid  = threadIdx.x;
    int wave = tid >> 6, lane = tid & 63;
    int m = lane & 15, q = lane >> 4;
    int base = blockIdx.x * 64 + wave * 16;

    // B frags (W1 is 8 KB, L1-cached after first touch)
    short8 bfrag[4];
    #pragma unroll
    for (int kc = 0; kc < 4; ++kc) {
        #pragma unroll
        for (int j = 0; j < 8; ++j)
            bfrag[kc][j] = (short)bf16_rne(W1[(kc * 32 + q * 8 + j) * HID + m]);
    }

    int rowa = base + m; if (rowa > n - 1) rowa = n - 1;
    const float* xr = x + (size_t)rowa * NFEAT;
    f32x4 acc = {0.f, 0.f, 0.f, 0.f};
    #pragma unroll
    for (int kc = 0; kc < 4; ++kc) {
        float4 a0 = *(const float4*)(xr + kc * 32 + q * 8);
        float4 a1 = *(const float4*)(xr + kc * 32 + q * 8 + 4);
        short8 af;
        af[0] = (short)bf16_rne(a0.x); af[1] = (short)bf16_rne(a0.y);
        af[2] = (short)bf16_rne(a0.z); af[3] = (short)bf16_rne(a0.w);
        af[4] = (short)bf16_rne(a1.x); af[5] = (short)bf16_rne(a1.y);
        af[6] = (short)bf16_rne(a1.z); af[7] = (short)bf16_rne(a1.w);
        acc = __builtin_amdgcn_mfma_f32_16x16x32_bf16(af, bfrag[kc], acc, 0, 0, 0);
    }
    #pragma unroll
    for (int reg = 0; reg < 4; ++reg) {
        int rowd = base + q * 4 + reg;
        if (rowd < n)
            h1b[(size_t)rowd * HID + m] = (unsigned short)bf16_rne(acc[reg]);
    }
}

// ---------- gather layer 1: pipelined fixed-point LDS accumulation, bf16 out ----------
__global__ __launch_bounds__(512) void gather1_kernel(const uint4* __restrict__ hq,
                                                      const int* __restrict__ cursor,
                                                      const int2* __restrict__ slab,
                                                      uint4* __restrict__ outb, int n)
{
    __shared__ int accum[BNODES * APAD];   // 8.7 KB, [dl][f] pad-17
    int tid = threadIdx.x;
    #pragma unroll
    for (int i = tid; i < BNODES * APAD; i += 512) accum[i] = 0;
    __syncthreads();

    int b = blockIdx.x;
    int beg = b * CAP;
    int cnt = cursor[b]; if (cnt > CAP) cnt = CAP;
    int total = cnt * 2;                  // 2 lanes per edge, 8 feats each

    int i0 = tid, i1 = tid + 512;
    int2 e0, e1; uint4 q0;
    if (i0 < total) e0 = slab[beg + (i0 >> 1)];
    if (i1 < total) e1 = slab[beg + (i1 >> 1)];
    if (i0 < total) q0 = hq[(size_t)(e0.x & 0xFFFFF) * 2 + (i0 & 1)];

    while (i0 < total) {
        uint4 q1;
        if (i1 < total) q1 = hq[(size_t)(e1.x & 0xFFFFF) * 2 + (i1 & 1)];
        int i2 = i1 + 512;
        int2 e2;
        if (i2 < total) e2 = slab[beg + (i2 >> 1)];

        int p  = i0 & 1;
        int dl = (e0.x >> 20) & (BNODES - 1);
        float wsc = __int_as_float(e0.y) * SCALE1;
        int* a = &accum[dl * APAD + p * 8];
        atomicAdd(a + 0, __float2int_rn(wsc * bf_lo(q0.x)));
        atomicAdd(a + 1, __float2int_rn(wsc * bf_hi(q0.x)));
        atomicAdd(a + 2, __float2int_rn(wsc * bf_lo(q0.y)));
        atomicAdd(a + 3, __float2int_rn(wsc * bf_hi(q0.y)));
        atomicAdd(a + 4, __float2int_rn(wsc * bf_lo(q0.z)));
        atomicAdd(a + 5, __float2int_rn(wsc * bf_hi(q0.z)));
        atomicAdd(a + 6, __float2int_rn(wsc * bf_lo(q0.w)));
        atomicAdd(a + 7, __float2int_rn(wsc * bf_hi(q0.w)));

        e0 = e1; e1 = e2; q0 = q1; i0 = i1; i1 = i2;
    }
    __syncthreads();

    const float inv = 1.0f / SCALE1;
    if (tid < BNODES * 2) {
        int dl = tid >> 1, p = tid & 1;
        int node = (b << BSHIFT) + dl;
        if (node < n) {
            uint4 qs = hq[(size_t)node * 2 + p];
            const int* a = &accum[dl * APAD + p * 8];
            uint4 o;
            o.x = bf16_rne((float)a[0] * inv + bf_lo(qs.x)) |
                  (bf16_rne((float)a[1] * inv + bf_hi(qs.x)) << 16);
            o.y = bf16_rne((float)a[2] * inv + bf_lo(qs.y)) |
                  (bf16_rne((float)a[3] * inv + bf_hi(qs.y)) << 16);
            o.z = bf16_rne((float)a[4] * inv + bf_lo(qs.z)) |
                  (bf16_rne((float)a[5] * inv + bf_hi(qs.z)) << 16);
            o.w = bf16_rne((float)a[6] * inv + bf_lo(qs.w)) |
                  (bf16_rne((float)a[7] * inv + bf_hi(qs.w)) << 16);
            outb[(size_t)node * 2 + p] = o;
        }
    }
}

// ---------- gather layer 2 + W2 projection + log_softmax, fused ----------
#define ZPAD 41
__global__ __launch_bounds__(512) void gather2_lsm_kernel(const uint4* __restrict__ hq,
                                                          const int* __restrict__ cursor,
                                                          const int2* __restrict__ slab,
                                                          const float* __restrict__ W2,
                                                          float* __restrict__ out, int n)
{
    __shared__ int   accum[BNODES * APAD];  // 8.7 KB
    __shared__ float w2s[HID * NCLS];       // 2.56 KB
    __shared__ float zbuf[BNODES * ZPAD];   // 21 KB
    int tid = threadIdx.x;
    #pragma unroll
    for (int i = tid; i < BNODES * APAD; i += 512) accum[i] = 0;
    for (int i = tid; i < HID * NCLS; i += 512) w2s[i] = W2[i];
    __syncthreads();

    int b = blockIdx.x;
    int beg = b * CAP;
    int cnt = cursor[b]; if (cnt > CAP) cnt = CAP;
    int node0 = b << BSHIFT;
    int total = cnt * 2;

    int i0 = tid, i1 = tid + 512;
    int2 e0, e1; uint4 q0;
    if (i0 < total) e0 = slab[beg + (i0 >> 1)];
    if (i1 < total) e1 = slab[beg + (i1 >> 1)];
    if (i0 < total) q0 = hq[(size_t)(e0.x & 0xFFFFF) * 2 + (i0 & 1)];

    while (i0 < total) {
        uint4 q1;
        if (i1 < total) q1 = hq[(size_t)(e1.x & 0xFFFFF) * 2 + (i1 & 1)];
        int i2 = i1 + 512;
        int2 e2;
        if (i2 < total) e2 = slab[beg + (i2 >> 1)];

        int p  = i0 & 1;
        int dl = (e0.x >> 20) & (BNODES - 1);
        float wsc = __int_as_float(e0.y) * SCALE2;
        int* a = &accum[dl * APAD + p * 8];
        atomicAdd(a + 0, __float2int_rn(wsc * bf_lo(q0.x)));
        atomicAdd(a + 1, __float2int_rn(wsc * bf_hi(q0.x)));
        atomicAdd(a + 2, __float2int_rn(wsc * bf_lo(q0.y)));
        atomicAdd(a + 3, __float2int_rn(wsc * bf_hi(q0.y)));
        atomicAdd(a + 4, __float2int_rn(wsc * bf_lo(q0.z)));
        atomicAdd(a + 5, __float2int_rn(wsc * bf_hi(q0.z)));
        atomicAdd(a + 6, __float2int_rn(wsc * bf_lo(q0.w)));
        atomicAdd(a + 7, __float2int_rn(wsc * bf_hi(q0.w)));

        e0 = e1; e1 = e2; q0 = q1; i0 = i1; i1 = i2;
    }
    __syncthreads();

    const float inv = 1.0f / SCALE2;
    if (tid < BNODES) {
        int dl = tid;
        int node = node0 + dl;
        if (node < n) {
            uint4 qa = hq[(size_t)node * 2 + 0];
            uint4 qb = hq[(size_t)node * 2 + 1];
            float r[HID];
            const int* a = &accum[dl * APAD];
            r[0]  = (float)a[ 0] * inv + bf_lo(qa.x);
            r[1]  = (float)a[ 1] * inv + bf_hi(qa.x);
            r[2]  = (float)a[ 2] * inv + bf_lo(qa.y);
            r[3]  = (float)a[ 3] * inv + bf_hi(qa.y);
            r[4]  = (float)a[ 4] * inv + bf_lo(qa.z);
            r[5]  = (float)a[ 5] * inv + bf_hi(qa.z);
            r[6]  = (float)a[ 6] * inv + bf_lo(qa.w);
            r[7]  = (float)a[ 7] * inv + bf_hi(qa.w);
            r[8]  = (float)a[ 8] * inv + bf_lo(qb.x);
            r[9]  = (float)a[ 9] * inv + bf_hi(qb.x);
            r[10] = (float)a[10] * inv + bf_lo(qb.y);
            r[11] = (float)a[11] * inv + bf_hi(qb.y);
            r[12] = (float)a[12] * inv + bf_lo(qb.z);
            r[13] = (float)a[13] * inv + bf_hi(qb.z);
            r[14] = (float)a[14] * inv + bf_lo(qb.w);
            r[15] = (float)a[15] * inv + bf_hi(qb.w);

            float z[NCLS];
            #pragma unroll
            for (int j = 0; j < NCLS; ++j) z[j] = 0.f;
            #pragma unroll
            for (int f = 0; f < HID; ++f) {
                float rf = r[f];
                #pragma unroll
                for (int j = 0; j < NCLS; ++j)
                    z[j] += rf * w2s[f * NCLS + j];   // broadcast reads
            }
            float m = z[0];
            #pragma unroll
            for (int j = 1; j < NCLS; ++j) m = fmaxf(m, z[j]);
            float ssum = 0.f;
            #pragma unroll
            for (int j = 0; j < NCLS; ++j) ssum += __expf(z[j] - m);
            float l = m + __logf(ssum);
            #pragma unroll
            for (int j = 0; j < NCLS; ++j) zbuf[dl * ZPAD + j] = z[j] - l;
        }
    }
    __syncthreads();

    for (int i = tid; i < BNODES * NCLS; i += 512) {
        int nl = i / NCLS, j = i - nl * NCLS;
        if (node0 + nl < n)
            out[(size_t)node0 * NCLS + i] = zbuf[nl * ZPAD + j];
    }
}

extern "C" void kernel_launch(void* const* d_in, const int* in_sizes, int n_in,
                              void* d_out, int out_size, void* d_ws, size_t ws_size,
                              hipStream_t stream)
{
    const float* x  = (const float*)d_in[0];
    const float* ew = (const float*)d_in[1];
    const float* W1 = (const float*)d_in[2];
    const float* W2 = (const float*)d_in[3];
    const int*   ei = (const int*)d_in[4];

    int n = in_sizes[0] / NFEAT;     // 100000
    int E = in_sizes[1];             // 1600000
    const int* src = ei;
    const int* dst = ei + E;
    float* out = (float*)d_out;

    int nbuck = (n + BNODES - 1) >> BSHIFT;           // 782
    int nbin  = (E + BIN_CHUNK - 1) / BIN_CHUNK;      // 391

    // ---- workspace layout ----
    char* w = (char*)d_ws;
    int*  cursor = (int*)w;  w += NBUCK_MAX * 4;
    w = (char*)(((size_t)w + 15) & ~(size_t)15);
    int2* slab   = (int2*)w; w += (size_t)NBUCK_MAX * CAP * 8;           // 16 MB
    unsigned short* h1b = (unsigned short*)w; w += (size_t)n * HID * 2;  // 3.2 MB bf16
    unsigned short* h2b = (unsigned short*)w; w += (size_t)n * HID * 2;  // 3.2 MB bf16

    hipMemsetAsync(cursor, 0, (size_t)nbuck * 4, stream);
    bin_kernel<<<nbin, 256, 0, stream>>>(src, dst, ew, cursor, slab, E, nbuck);
    gemm1_mfma_kernel<<<(n + 63) / 64, 256, 0, stream>>>(x, W1, h1b, n);
    gather1_kernel<<<nbuck, 512, 0, stream>>>((const uint4*)h1b, cursor, slab,
                                              (uint4*)h2b, n);
    gather2_lsm_kernel<<<nbuck, 512, 0, stream>>>((const uint4*)h2b, cursor, slab,
                                                  W2, out, n);
}

// Round 10
// 171.728 us; speedup vs baseline: 1.0832x; 1.0188x over previous
//
#include <hip/hip_runtime.h>

#define NFEAT 128
#define HID 16
#define NCLS 40
#define BSHIFT 7                 // 128 nodes per bucket
#define BNODES 128
#define CAP 2560                 // slab capacity per bucket (Poisson mean ~2046, 11 sigma)
#define NBUCK_MAX 800            // >= ceil(100000/128)=782
#define BIN_CHUNK 4096           // edges per bin block (16 per thread)
#define APAD 17                  // accum stride: lane's 8 atomics -> 8 distinct banks

#define SCALE1 262144.0f         // 2^18 — layer-1 message quantization
#define SCALE2 65536.0f          // 2^16 — layer-2 message quantization

typedef __attribute__((ext_vector_type(8))) short short8;   // 8 x bf16 (4 VGPRs)
typedef __attribute__((ext_vector_type(4))) float f32x4;

__device__ __forceinline__ unsigned bf16_rne(float f) {
    unsigned u = __float_as_uint(f);
    return (u + 0x7FFFu + ((u >> 16) & 1u)) >> 16;
}
__device__ __forceinline__ float bf_lo(unsigned u) { return __uint_as_float(u << 16); }
__device__ __forceinline__ float bf_hi(unsigned u) { return __uint_as_float(u & 0xFFFF0000u); }

// ---------- cursor init: plain kernel node (replay-safe by construction) ----------
__global__ __launch_bounds__(256) void zero_kernel(int* __restrict__ p, int m)
{
    int i = blockIdx.x * 256 + threadIdx.x;
    if (i < m) p[i] = 0;
}

// ---------- bin: bucket slabs ----------
// slab[b*CAP + i] = { src | (dst&127)<<20 , bits(weight) }, cursor[b] = count
__global__ __launch_bounds__(256) void bin_kernel(const int* __restrict__ src,
                                                  const int* __restrict__ dst,
                                                  const float* __restrict__ ew,
                                                  int* __restrict__ cursor,
                                                  int2* __restrict__ slab,
                                                  int E, int nbuck)
{
    __shared__ int hist[NBUCK_MAX];
    __shared__ int runbase[NBUCK_MAX];
    int tid = threadIdx.x;
    for (int i = tid; i < NBUCK_MAX; i += 256) hist[i] = 0;
    __syncthreads();

    int base = blockIdx.x * BIN_CHUNK;
    int myd[16], mys[16], myw[16];
    #pragma unroll
    for (int k = 0; k < 16; ++k) {
        int e = base + k * 256 + tid;
        if (e < E) {
            myd[k] = dst[e];
            mys[k] = src[e];
            myw[k] = __float_as_int(ew[e]);
            atomicAdd(&hist[myd[k] >> BSHIFT], 1);       // native ds_add
        } else myd[k] = -1;
    }
    __syncthreads();
    for (int i = tid; i < nbuck; i += 256) {
        int c = hist[i];
        runbase[i] = c ? (i * CAP + atomicAdd(&cursor[i], c)) : 0;
        hist[i] = 0;                                     // reuse as intra-block cursor
    }
    __syncthreads();
    #pragma unroll
    for (int k = 0; k < 16; ++k) {
        int d = myd[k];
        if (d >= 0) {
            int b = d >> BSHIFT;
            int pos = runbase[b] + atomicAdd(&hist[b], 1);
            if (pos < (b + 1) * CAP)                     // overflow guard
                slab[pos] = make_int2(mys[k] | ((d & (BNODES - 1)) << 20), myw[k]);
        }
    }
}

// ---------- gemm1: h1b = bf16(x @ W1) via MFMA, no LDS ----------
__global__ __launch_bounds__(256) void gemm1_mfma_kernel(const float* __restrict__ x,
                                                         const float* __restrict__ W1,
                                                         unsigned short* __restrict__ h1b,
                                                         int n)
{
    int tid  = threadIdx.x;
    int wave = tid >> 6, lane = tid & 63;
    int m = lane & 15, q = lane >> 4;
    int base = blockIdx.x * 64 + wave * 16;

    short8 bfrag[4];
    #pragma unroll
    for (int kc = 0; kc < 4; ++kc) {
        #pragma unroll
        for (int j = 0; j < 8; ++j)
            bfrag[kc][j] = (short)bf16_rne(W1[(kc * 32 + q * 8 + j) * HID + m]);
    }

    int rowa = base + m; if (rowa > n - 1) rowa = n - 1;
    const float* xr = x + (size_t)rowa * NFEAT;
    f32x4 acc = {0.f, 0.f, 0.f, 0.f};
    #pragma unroll
    for (int kc = 0; kc < 4; ++kc) {
        float4 a0 = *(const float4*)(xr + kc * 32 + q * 8);
        float4 a1 = *(const float4*)(xr + kc * 32 + q * 8 + 4);
        short8 af;
        af[0] = (short)bf16_rne(a0.x); af[1] = (short)bf16_rne(a0.y);
        af[2] = (short)bf16_rne(a0.z); af[3] = (short)bf16_rne(a0.w);
        af[4] = (short)bf16_rne(a1.x); af[5] = (short)bf16_rne(a1.y);
        af[6] = (short)bf16_rne(a1.z); af[7] = (short)bf16_rne(a1.w);
        acc = __builtin_amdgcn_mfma_f32_16x16x32_bf16(af, bfrag[kc], acc, 0, 0, 0);
    }
    #pragma unroll
    for (int reg = 0; reg < 4; ++reg) {
        int rowd = base + q * 4 + reg;
        if (rowd < n)
            h1b[(size_t)rowd * HID + m] = (unsigned short)bf16_rne(acc[reg]);
    }
}

// ---------- gather layer 1: pipelined fixed-point LDS accumulation, bf16 out ----------
__global__ __launch_bounds__(512) void gather1_kernel(const uint4* __restrict__ hq,
                                                      const int* __restrict__ cursor,
                                                      const int2* __restrict__ slab,
                                                      uint4* __restrict__ outb, int n)
{
    __shared__ int accum[BNODES * APAD];   // 8.7 KB, [dl][f] pad-17
    int tid = threadIdx.x;
    #pragma unroll
    for (int i = tid; i < BNODES * APAD; i += 512) accum[i] = 0;
    __syncthreads();

    int b = blockIdx.x;
    int beg = b * CAP;
    int cnt = cursor[b]; if (cnt > CAP) cnt = CAP;
    int total = cnt * 2;                  // 2 lanes per edge, 8 feats each

    int i0 = tid, i1 = tid + 512;
    int2 e0, e1; uint4 q0;
    if (i0 < total) e0 = slab[beg + (i0 >> 1)];
    if (i1 < total) e1 = slab[beg + (i1 >> 1)];
    if (i0 < total) q0 = hq[(size_t)(e0.x & 0xFFFFF) * 2 + (i0 & 1)];

    while (i0 < total) {
        uint4 q1;
        if (i1 < total) q1 = hq[(size_t)(e1.x & 0xFFFFF) * 2 + (i1 & 1)];
        int i2 = i1 + 512;
        int2 e2;
        if (i2 < total) e2 = slab[beg + (i2 >> 1)];

        int p  = i0 & 1;
        int dl = (e0.x >> 20) & (BNODES - 1);
        float wsc = __int_as_float(e0.y) * SCALE1;
        int* a = &accum[dl * APAD + p * 8];
        atomicAdd(a + 0, __float2int_rn(wsc * bf_lo(q0.x)));
        atomicAdd(a + 1, __float2int_rn(wsc * bf_hi(q0.x)));
        atomicAdd(a + 2, __float2int_rn(wsc * bf_lo(q0.y)));
        atomicAdd(a + 3, __float2int_rn(wsc * bf_hi(q0.y)));
        atomicAdd(a + 4, __float2int_rn(wsc * bf_lo(q0.z)));
        atomicAdd(a + 5, __float2int_rn(wsc * bf_hi(q0.z)));
        atomicAdd(a + 6, __float2int_rn(wsc * bf_lo(q0.w)));
        atomicAdd(a + 7, __float2int_rn(wsc * bf_hi(q0.w)));

        e0 = e1; e1 = e2; q0 = q1; i0 = i1; i1 = i2;
    }
    __syncthreads();

    const float inv = 1.0f / SCALE1;
    if (tid < BNODES * 2) {
        int dl = tid >> 1, p = tid & 1;
        int node = (b << BSHIFT) + dl;
        if (node < n) {
            uint4 qs = hq[(size_t)node * 2 + p];
            const int* a = &accum[dl * APAD + p * 8];
            uint4 o;
            o.x = bf16_rne((float)a[0] * inv + bf_lo(qs.x)) |
                  (bf16_rne((float)a[1] * inv + bf_hi(qs.x)) << 16);
            o.y = bf16_rne((float)a[2] * inv + bf_lo(qs.y)) |
                  (bf16_rne((float)a[3] * inv + bf_hi(qs.y)) << 16);
            o.z = bf16_rne((float)a[4] * inv + bf_lo(qs.z)) |
                  (bf16_rne((float)a[5] * inv + bf_hi(qs.z)) << 16);
            o.w = bf16_rne((float)a[6] * inv + bf_lo(qs.w)) |
                  (bf16_rne((float)a[7] * inv + bf_hi(qs.w)) << 16);
            outb[(size_t)node * 2 + p] = o;
        }
    }
}

// ---------- gather layer 2 + W2 projection + log_softmax, fused ----------
#define ZPAD 41
__global__ __launch_bounds__(512) void gather2_lsm_kernel(const uint4* __restrict__ hq,
                                                          const int* __restrict__ cursor,
                                                          const int2* __restrict__ slab,
                                                          const float* __restrict__ W2,
                                                          float* __restrict__ out, int n)
{
    __shared__ int   accum[BNODES * APAD];  // 8.7 KB
    __shared__ float w2s[HID * NCLS];       // 2.56 KB
    __shared__ float zbuf[BNODES * ZPAD];   // 21 KB
    int tid = threadIdx.x;
    #pragma unroll
    for (int i = tid; i < BNODES * APAD; i += 512) accum[i] = 0;
    for (int i = tid; i < HID * NCLS; i += 512) w2s[i] = W2[i];
    __syncthreads();

    int b = blockIdx.x;
    int beg = b * CAP;
    int cnt = cursor[b]; if (cnt > CAP) cnt = CAP;
    int node0 = b << BSHIFT;
    int total = cnt * 2;

    int i0 = tid, i1 = tid + 512;
    int2 e0, e1; uint4 q0;
    if (i0 < total) e0 = slab[beg + (i0 >> 1)];
    if (i1 < total) e1 = slab[beg + (i1 >> 1)];
    if (i0 < total) q0 = hq[(size_t)(e0.x & 0xFFFFF) * 2 + (i0 & 1)];

    while (i0 < total) {
        uint4 q1;
        if (i1 < total) q1 = hq[(size_t)(e1.x & 0xFFFFF) * 2 + (i1 & 1)];
        int i2 = i1 + 512;
        int2 e2;
        if (i2 < total) e2 = slab[beg + (i2 >> 1)];

        int p  = i0 & 1;
        int dl = (e0.x >> 20) & (BNODES - 1);
        float wsc = __int_as_float(e0.y) * SCALE2;
        int* a = &accum[dl * APAD + p * 8];
        atomicAdd(a + 0, __float2int_rn(wsc * bf_lo(q0.x)));
        atomicAdd(a + 1, __float2int_rn(wsc * bf_hi(q0.x)));
        atomicAdd(a + 2, __float2int_rn(wsc * bf_lo(q0.y)));
        atomicAdd(a + 3, __float2int_rn(wsc * bf_hi(q0.y)));
        atomicAdd(a + 4, __float2int_rn(wsc * bf_lo(q0.z)));
        atomicAdd(a + 5, __float2int_rn(wsc * bf_hi(q0.z)));
        atomicAdd(a + 6, __float2int_rn(wsc * bf_lo(q0.w)));
        atomicAdd(a + 7, __float2int_rn(wsc * bf_hi(q0.w)));

        e0 = e1; e1 = e2; q0 = q1; i0 = i1; i1 = i2;
    }
    __syncthreads();

    const float inv = 1.0f / SCALE2;
    if (tid < BNODES) {
        int dl = tid;
        int node = node0 + dl;
        if (node < n) {
            uint4 qa = hq[(size_t)node * 2 + 0];
            uint4 qb = hq[(size_t)node * 2 + 1];
            float r[HID];
            const int* a = &accum[dl * APAD];
            r[0]  = (float)a[ 0] * inv + bf_lo(qa.x);
            r[1]  = (float)a[ 1] * inv + bf_hi(qa.x);
            r[2]  = (float)a[ 2] * inv + bf_lo(qa.y);
            r[3]  = (float)a[ 3] * inv + bf_hi(qa.y);
            r[4]  = (float)a[ 4] * inv + bf_lo(qa.z);
            r[5]  = (float)a[ 5] * inv + bf_hi(qa.z);
            r[6]  = (float)a[ 6] * inv + bf_lo(qa.w);
            r[7]  = (float)a[ 7] * inv + bf_hi(qa.w);
            r[8]  = (float)a[ 8] * inv + bf_lo(qb.x);
            r[9]  = (float)a[ 9] * inv + bf_hi(qb.x);
            r[10] = (float)a[10] * inv + bf_lo(qb.y);
            r[11] = (float)a[11] * inv + bf_hi(qb.y);
            r[12] = (float)a[12] * inv + bf_lo(qb.z);
            r[13] = (float)a[13] * inv + bf_hi(qb.z);
            r[14] = (float)a[14] * inv + bf_lo(qb.w);
            r[15] = (float)a[15] * inv + bf_hi(qb.w);

            float z[NCLS];
            #pragma unroll
            for (int j = 0; j < NCLS; ++j) z[j] = 0.f;
            #pragma unroll
            for (int f = 0; f < HID; ++f) {
                float rf = r[f];
                #pragma unroll
                for (int j = 0; j < NCLS; ++j)
                    z[j] += rf * w2s[f * NCLS + j];   // broadcast reads
            }
            float m = z[0];
            #pragma unroll
            for (int j = 1; j < NCLS; ++j) m = fmaxf(m, z[j]);
            float ssum = 0.f;
            #pragma unroll
            for (int j = 0; j < NCLS; ++j) ssum += __expf(z[j] - m);
            float l = m + __logf(ssum);
            #pragma unroll
            for (int j = 0; j < NCLS; ++j) zbuf[dl * ZPAD + j] = z[j] - l;
        }
    }
    __syncthreads();

    for (int i = tid; i < BNODES * NCLS; i += 512) {
        int nl = i / NCLS, j = i - nl * NCLS;
        if (node0 + nl < n)
            out[(size_t)node0 * NCLS + i] = zbuf[nl * ZPAD + j];
    }
}

extern "C" void kernel_launch(void* const* d_in, const int* in_sizes, int n_in,
                              void* d_out, int out_size, void* d_ws, size_t ws_size,
                              hipStream_t stream)
{
    const float* x  = (const float*)d_in[0];
    const float* ew = (const float*)d_in[1];
    const float* W1 = (const float*)d_in[2];
    const float* W2 = (const float*)d_in[3];
    const int*   ei = (const int*)d_in[4];

    int n = in_sizes[0] / NFEAT;     // 100000
    int E = in_sizes[1];             // 1600000
    const int* src = ei;
    const int* dst = ei + E;
    float* out = (float*)d_out;

    int nbuck = (n + BNODES - 1) >> BSHIFT;           // 782
    int nbin  = (E + BIN_CHUNK - 1) / BIN_CHUNK;      // 391

    // ---- workspace layout ----
    char* w = (char*)d_ws;
    int*  cursor = (int*)w;  w += NBUCK_MAX * 4;
    w = (char*)(((size_t)w + 15) & ~(size_t)15);
    int2* slab   = (int2*)w; w += (size_t)NBUCK_MAX * CAP * 8;           // 16 MB
    unsigned short* h1b = (unsigned short*)w; w += (size_t)n * HID * 2;  // 3.2 MB bf16
    unsigned short* h2b = (unsigned short*)w; w += (size_t)n * HID * 2;  // 3.2 MB bf16

    zero_kernel<<<(NBUCK_MAX + 255) / 256, 256, 0, stream>>>(cursor, NBUCK_MAX);
    bin_kernel<<<nbin, 256, 0, stream>>>(src, dst, ew, cursor, slab, E, nbuck);
    gemm1_mfma_kernel<<<(n + 63) / 64, 256, 0, stream>>>(x, W1, h1b, n);
    gather1_kernel<<<nbuck, 512, 0, stream>>>((const uint4*)h1b, cursor, slab,
                                              (uint4*)h2b, n);
    gather2_lsm_kernel<<<nbuck, 512, 0, stream>>>((const uint4*)h2b, cursor, slab,
                                                  W2, out, n);
}